// Round 10
// baseline (22.086 us; speedup 1.0000x reference)
//
#include <hip/hip_runtime.h>
#include <math.h>

#define NB 512
#define NK 64
#define HW 400
#define NC 10
#define NWAVE 8

__device__ __forceinline__ unsigned sad16(unsigned a, unsigned b, unsigned c) {
#if __has_builtin(__builtin_amdgcn_sad_u16)
    return __builtin_amdgcn_sad_u16(a, b, c);
#else
    unsigned d;
    asm("v_sad_u16 %0, %1, %2, %3" : "=v"(d) : "v"(a), "v"(b), "v"(c));
    return d;
#endif
}

__global__ __launch_bounds__(512, 2) void geneo_mlp_kernel(
    const float* __restrict__ x,        // (B,1,20,20)
    const float* __restrict__ patterns, // (K,1,5,5)
    const float* __restrict__ w2,       // (1,K)
    const float* __restrict__ b2,       // (1,)
    const float* __restrict__ wf,       // (NC,400)
    const float* __restrict__ bf,       // (NC,)
    float* __restrict__ out)            // (B,NC)
{
    // xq4[j]: quantized padded image (24x24 u16-in-u32), cols shifted left by j.
    // pqd4[j]: vertical-pair rows: row r packs (row r lo16, row r+1 hi16).
    // Tile tc (cols tc*5..tc*5+4) reads copy j=tc at word base 4*tc (16B-aligned).
    __shared__ __align__(16) unsigned xq4[4][576];
    __shared__ __align__(16) unsigned pqd4[4][552];
    __shared__ __align__(16) float pat_lds[NK * 25];
    __shared__ unsigned redbest[NWAVE][NK];
    __shared__ float2 pixcv[NK];        // (F*w2, bitcast pix)
    __shared__ float colsum[NC];        // sum_p wf[c,p]
    __shared__ float redout[NC];        // sum_k delta_k * wf[c,pix_k]

    const int tid  = threadIdx.x;
    const int b    = blockIdx.x;
    const int lane = tid & 63;
    const int wave = tid >> 6;

    // ---- stage: all 4 shifted quantized copies direct from global (L1-hot)
    //      + patterns coalesced. One barrier after. ----
    for (int i = tid; i < 4 * 576; i += 512) {
        const int j = i >> 9 >> 0; // placeholder
    }
    // (rewritten without the placeholder loop below)
    {
        for (int i = tid; i < 4 * 576; i += 512) {
            const int j = i / 576;
            const int w = i - j * 576;
            const int ph = w / 24;
            const int pc = (w - ph * 24) + j;     // shifted padded col
            float v = 0.f;
            if (ph >= 2 && ph < 22 && pc >= 2 && pc < 22)
                v = x[b * HW + (ph - 2) * 20 + (pc - 2)];
            xq4[j][w] = (unsigned)(v * 65535.f + 0.5f);
        }
        if (tid < 400)
            reinterpret_cast<float4*>(pat_lds)[tid] =
                reinterpret_cast<const float4*>(patterns)[tid];
    }
    __syncthreads();

    // ---- vertical-pair rows for all 4 copies + per-lane pattern quantize ----
    for (int i = tid; i < 4 * 552; i += 512) {
        const int j = i / 552;
        const int w = i - j * 552;
        pqd4[j][w] = xq4[j][w] | (xq4[j][w + 24] << 16);
    }
    unsigned vp01[5], vp23[5], p4v[5];
    #pragma unroll
    for (int c = 0; c < 5; ++c) {
        const unsigned q0 = (unsigned)(pat_lds[lane * 25 +  0 + c] * 65535.f + 0.5f);
        const unsigned q1 = (unsigned)(pat_lds[lane * 25 +  5 + c] * 65535.f + 0.5f);
        const unsigned q2 = (unsigned)(pat_lds[lane * 25 + 10 + c] * 65535.f + 0.5f);
        const unsigned q3 = (unsigned)(pat_lds[lane * 25 + 15 + c] * 65535.f + 0.5f);
        const unsigned q4 = (unsigned)(pat_lds[lane * 25 + 20 + c] * 65535.f + 0.5f);
        vp01[c] = q0 | (q1 << 16);
        vp23[c] = q2 | (q3 << 16);
        p4v[c]  = q4;
    }
    __syncthreads();

    // ---- MAIN: wave = (tr, tc): rows tr*10..tr*10+9, cols tc*5..tc*5+4 ----
    const int tr   = wave >> 2;         // 0..1
    const int tc   = wave & 3;          // 0..3
    const int base = 4 * tc;            // word base in copy tc (16B-aligned)
    unsigned best  = 0xFFFFFFFFu;       // (s<<9 | pix): min = lexicographic

    #pragma unroll 1
    for (int r = 0; r < 10; ++r) {
        const int h = tr * 10 + r;
        const unsigned* r01 = &pqd4[tc][h * 24 + base];
        const unsigned* r23 = &pqd4[tc][(h + 2) * 24 + base];
        const unsigned* r4  = &xq4[tc][(h + 4) * 24 + base];
        uint4 A0 = *reinterpret_cast<const uint4*>(r01);
        uint4 A1 = *reinterpret_cast<const uint4*>(r01 + 4);
        unsigned A8 = r01[8];
        uint4 B0 = *reinterpret_cast<const uint4*>(r23);
        uint4 B1 = *reinterpret_cast<const uint4*>(r23 + 4);
        unsigned B8 = r23[8];
        uint4 C0 = *reinterpret_cast<const uint4*>(r4);
        uint4 C1 = *reinterpret_cast<const uint4*>(r4 + 4);
        unsigned C8 = r4[8];
        const unsigned W01[9] = {A0.x, A0.y, A0.z, A0.w, A1.x, A1.y, A1.z, A1.w, A8};
        const unsigned W23[9] = {B0.x, B0.y, B0.z, B0.w, B1.x, B1.y, B1.z, B1.w, B8};
        const unsigned W4 [9] = {C0.x, C0.y, C0.z, C0.w, C1.x, C1.y, C1.z, C1.w, C8};
        #pragma unroll
        for (int px = 0; px < 5; ++px) {
            unsigned s = 0;
            #pragma unroll
            for (int dx = 0; dx < 5; ++dx) {
                s = sad16(W01[px + dx], vp01[dx], s);
                s = sad16(W23[px + dx], vp23[dx], s);
                s = sad16(W4 [px + dx], p4v [dx], s);
            }
            const unsigned pk = (s << 9) | (unsigned)(h * 20 + tc * 5 + px);
            best = min(best, pk);
        }
    }
    redbest[wave][lane] = best;
    __syncthreads();

    // ---- E1 (all waves): colsum[c] = sum_p wf[c,p], classes strided by 8 ----
    for (int c = wave; c < NC; c += NWAVE) {
        float sc = 0.f;
        for (int p = lane; p < HW; p += 64) sc += wf[c * HW + p];
        #pragma unroll
        for (int off = 32; off >= 1; off >>= 1) sc += __shfl_down(sc, off);
        if (lane == 0) colsum[c] = sc;
    }
    // ---- E2a (wave 7): combine 8 tiles per k; pixcv = (F*w2, pix) ----
    if (wave == NWAVE - 1) {
        unsigned b0 = redbest[0][lane];
        #pragma unroll
        for (int w = 1; w < NWAVE; ++w) b0 = min(b0, redbest[w][lane]);
        const float F  = 1.f - (float)(b0 >> 9) * (1.f / (25.f * 65535.f));
        pixcv[lane] = make_float2(F * w2[lane], __int_as_float((int)(b0 & 511u)));
    }
    __syncthreads();

    // ---- E2b (wave 0): group by pixel, dedupe, 10-class partial ----
    if (wave == 0) {
        const int mypix = __float_as_int(pixcv[lane].y);
        float ssum = 0.f;
        int   firstj = 64;
        #pragma unroll 8
        for (int j = 0; j < NK; ++j) {
            const float2 pc = pixcv[j];
            if (__float_as_int(pc.y) == mypix) {
                ssum += pc.x;
                if (j < firstj) firstj = j;
            }
        }
        const float b2v = b2[0];
        const float t0  = 1.f / (1.f + expf(-b2v));
        const float t   = 1.f / (1.f + expf(-(b2v + ssum)));
        const float dlt = (firstj == lane) ? (t - t0) : 0.f;
        #pragma unroll
        for (int c = 0; c < NC; ++c) {
            float v = dlt * wf[c * HW + mypix];
            #pragma unroll
            for (int off = 32; off >= 1; off >>= 1) v += __shfl_down(v, off);
            if (lane == 0) redout[c] = v;
        }
    }
    __syncthreads();

    // ---- E3: final 10 outputs ----
    if (tid < NC) {
        const float b2v = b2[0];
        const float t0  = 1.f / (1.f + expf(-b2v));
        const float s   = t0 * colsum[tid] + redout[tid] + bf[tid];
        out[b * NC + tid] = 1.f / (1.f + expf(-s));
    }
}

extern "C" void kernel_launch(void* const* d_in, const int* in_sizes, int n_in,
                              void* d_out, int out_size, void* d_ws, size_t ws_size,
                              hipStream_t stream) {
    const float* x        = (const float*)d_in[0];
    const float* patterns = (const float*)d_in[1];
    const float* w2       = (const float*)d_in[2];
    const float* b2       = (const float*)d_in[3];
    const float* wf       = (const float*)d_in[4];
    const float* bf       = (const float*)d_in[5];
    float* out = (float*)d_out;

    geneo_mlp_kernel<<<NB, 512, 0, stream>>>(x, patterns, w2, b2, wf, bf, out);
}